// Round 2
// baseline (149.750 us; speedup 1.0000x reference)
//
#include <hip/hip_runtime.h>

#define N 8192
#define D 256
#define INV_TAU 14.285714285714286f
#define SCALE2 20.60992915555662f   // INV_TAU * log2(e)
#define EPSN 1e-6f
#define MAXM 48                     // max class size (binomial(8192,1/1024), mean 8)

// fused-lse geometry
#define RT 256            // rows per block (4 waves x 64 rows)
#define CT 64             // cols per LDS tile
#define CSPLIT 16         // column splits across blocks
#define CPB (N / CSPLIT)  // 512 cols per block
#define NTILES (CPB / CT) // 8 tiles

typedef unsigned int u32x4 __attribute__((ext_vector_type(4)));
typedef __bf16 bf16x8 __attribute__((ext_vector_type(8)));
typedef float f32x4 __attribute__((ext_vector_type(4)));

__device__ inline unsigned short f2bf(float x) {
    unsigned int u = __builtin_bit_cast(unsigned int, x);
    u += 0x7fffu + ((u >> 16) & 1u);   // RNE (finite inputs)
    return (unsigned short)(u >> 16);
}
__device__ inline float b2f(unsigned short u) {
    unsigned int x = (unsigned int)u << 16;
    return __builtin_bit_cast(float, x);
}
__device__ inline float fexp2(float x) {
#if __has_builtin(__builtin_amdgcn_exp2f)
    return __builtin_amdgcn_exp2f(x);
#else
    return __expf(x * 0.6931471805599453f);
#endif
}

// One wave per row: normalize -> bf16 (A linear, Bm chunk-XOR-swizzled),
// fp32 diag, zero rowsum, build per-class member lists.
__global__ void ntx_prep(const float* __restrict__ im, const float* __restrict__ rec,
                         const int* __restrict__ labels,
                         unsigned short* __restrict__ A, unsigned short* __restrict__ Bm,
                         float* __restrict__ diag, float* __restrict__ rowsum,
                         int* __restrict__ cnt, unsigned short* __restrict__ members) {
    const int wave = threadIdx.x >> 6;
    const int lane = threadIdx.x & 63;
    const int row  = blockIdx.x * 4 + wave;

    const float4 a = ((const float4*)(im  + (size_t)row * D))[lane];
    const float4 b = ((const float4*)(rec + (size_t)row * D))[lane];

    float ssa = a.x*a.x + a.y*a.y + a.z*a.z + a.w*a.w;
    float ssb = b.x*b.x + b.y*b.y + b.z*b.z + b.w*b.w;
    float dt  = a.x*b.x + a.y*b.y + a.z*b.z + a.w*b.w;
    #pragma unroll
    for (int o = 32; o; o >>= 1) {
        ssa += __shfl_xor(ssa, o);
        ssb += __shfl_xor(ssb, o);
        dt  += __shfl_xor(dt , o);
    }
    const float ra = 1.0f / fmaxf(sqrtf(ssa), EPSN);
    const float rb = 1.0f / fmaxf(sqrtf(ssb), EPSN);

    ushort4 pa, pb;
    pa.x = f2bf(a.x*ra); pa.y = f2bf(a.y*ra); pa.z = f2bf(a.z*ra); pa.w = f2bf(a.w*ra);
    pb.x = f2bf(b.x*rb); pb.y = f2bf(b.y*rb); pb.z = f2bf(b.z*rb); pb.w = f2bf(b.w*rb);

    *(ushort4*)(A + (size_t)row * D + lane * 4) = pa;
    // Bm: 16B chunk c of row r stored at chunk c ^ (r&7)
    const int chunk = lane >> 1;
    const int sw = chunk ^ (row & 7);
    *(ushort4*)(Bm + (size_t)row * D + sw * 8 + (lane & 1) * 4) = pb;

    if (lane == 0) {
        diag[row]   = dt * ra * rb * INV_TAU;
        rowsum[row] = 0.0f;
        const int lab = labels[row];
        const int u = atomicAdd(&cnt[lab], 1);
        if (u < MAXM) members[lab * MAXM + u] = (unsigned short)row;
    }
}

// Fused GEMM + UNMASKED sum-of-exp per row. 512 blocks x 256 threads.
__global__ __launch_bounds__(256, 2)
void ntx_lse(const unsigned short* __restrict__ A, const unsigned short* __restrict__ Bm,
             float* __restrict__ rowsum) {
    __shared__ __align__(16) unsigned short Bs[CT][D];   // 32 KB, physically swizzled

    const int wave = threadIdx.x >> 6;
    const int lane = threadIdx.x & 63;
    const int g    = lane >> 4;
    const int n16  = lane & 15;

    const int rowblk = blockIdx.x & (N / RT - 1);   // 0..31
    const int colblk = blockIdx.x >> 5;             // 0..15
    const int row0 = rowblk * RT + wave * 64;       // this wave's 64 rows
    const int col0 = colblk * CPB;

    // A fragments: 64 rows x K=256 in registers (128 VGPRs)
    bf16x8 afrag[4][8];
    #pragma unroll
    for (int rs = 0; rs < 4; ++rs) {
        const int r = row0 + rs * 16 + n16;
        #pragma unroll
        for (int k = 0; k < 8; ++k)
            afrag[rs][k] = __builtin_bit_cast(
                bf16x8, *(const u32x4*)(A + (size_t)r * D + k * 32 + g * 8));
    }

    float acc[4][4];
    #pragma unroll
    for (int rs = 0; rs < 4; ++rs)
        #pragma unroll
        for (int q = 0; q < 4; ++q) acc[rs][q] = 0.f;

    for (int t = 0; t < NTILES; ++t) {
        // async stage: tile is contiguous in (swizzled) Bm; 1KB per wave-instr
        const char* gsrc = (const char*)(Bm + (size_t)(col0 + t * CT) * D);
        char* lbase = (char*)&Bs[0][0];
        #pragma unroll
        for (int i = 0; i < 8; ++i) {
            const int off = (i * 4 + wave) * 1024;
            __builtin_amdgcn_global_load_lds(
                (const __attribute__((address_space(1))) void*)(gsrc + off + lane * 16),
                (__attribute__((address_space(3))) void*)(lbase + off),
                16, 0, 0);
        }
        __syncthreads();

        #pragma unroll
        for (int cs = 0; cs < 4; ++cs) {
            const int bc = cs * 16 + n16;
            bf16x8 bfrag[8];
            #pragma unroll
            for (int k = 0; k < 8; ++k)
                bfrag[k] = __builtin_bit_cast(
                    bf16x8, *(const u32x4*)(&Bs[bc][((k * 4 + g) ^ (bc & 7)) * 8]));

            #pragma unroll
            for (int rs = 0; rs < 4; ++rs) {
                f32x4 c = {0.f, 0.f, 0.f, 0.f};
                #pragma unroll
                for (int k = 0; k < 8; ++k)
                    c = __builtin_amdgcn_mfma_f32_16x16x32_bf16(
                            afrag[rs][k], bfrag[k], c, 0, 0, 0);
                #pragma unroll
                for (int q = 0; q < 4; ++q)
                    acc[rs][q] += fexp2(c[q] * SCALE2);   // no mask
            }
        }
        __syncthreads();
    }

    #pragma unroll
    for (int rs = 0; rs < 4; ++rs)
        #pragma unroll
        for (int q = 0; q < 4; ++q) {
            float v = acc[rs][q];
            v += __shfl_xor(v, 1);
            v += __shfl_xor(v, 2);
            v += __shfl_xor(v, 4);
            v += __shfl_xor(v, 8);
            if (n16 == 0)
                atomicAdd(&rowsum[row0 + rs * 16 + g * 4 + q], v);
        }
}

// Subtract exp of same-label off-diagonal entries. One wave per 4 rows.
__global__ void ntx_correct(const unsigned short* __restrict__ A,
                            const unsigned short* __restrict__ Bm,
                            const int* __restrict__ labels, const int* __restrict__ cnt,
                            const unsigned short* __restrict__ members,
                            float* __restrict__ rowsum) {
    const int wave = threadIdx.x >> 6;
    const int lane = threadIdx.x & 63;
    const int W = blockIdx.x * 4 + wave;   // 0..2047
    const int chunk = lane >> 1;

    for (int rr = 0; rr < 4; ++rr) {
        const int r = W * 4 + rr;
        const int lab = labels[r];
        const int m = min(cnt[lab], MAXM);
        const ushort4 av = *(const ushort4*)(A + (size_t)r * D + lane * 4);
        const float a0 = b2f(av.x), a1 = b2f(av.y), a2 = b2f(av.z), a3 = b2f(av.w);
        float sum = 0.f;
        for (int t = 0; t < m; ++t) {
            const int j = members[lab * MAXM + t];
            if (j == r) continue;
            const int sw = chunk ^ (j & 7);   // unswizzle Bm row j
            const ushort4 bv = *(const ushort4*)(Bm + (size_t)j * D + sw * 8 + (lane & 1) * 4);
            float d = a0 * b2f(bv.x) + a1 * b2f(bv.y) + a2 * b2f(bv.z) + a3 * b2f(bv.w);
            #pragma unroll
            for (int o = 32; o; o >>= 1) d += __shfl_xor(d, o);
            sum += fexp2(d * SCALE2);
        }
        if (lane == 0) rowsum[r] -= sum;
    }
}

// loss = mean(log(rowsum) - diag)
__global__ void ntx_finish(const float* __restrict__ diag,
                           const float* __restrict__ rowsum,
                           float* __restrict__ out) {
    __shared__ float red[256];
    float s = 0.f;
    for (int i = threadIdx.x; i < N; i += 256)
        s += logf(rowsum[i]) - diag[i];
    red[threadIdx.x] = s;
    __syncthreads();
    #pragma unroll
    for (int o = 128; o; o >>= 1) {
        if (threadIdx.x < o) red[threadIdx.x] += red[threadIdx.x + o];
        __syncthreads();
    }
    if (threadIdx.x == 0) out[0] = red[0] / (float)N;
}

extern "C" void kernel_launch(void* const* d_in, const int* in_sizes, int n_in,
                              void* d_out, int out_size, void* d_ws, size_t ws_size,
                              hipStream_t stream) {
    const float* im     = (const float*)d_in[0];
    const float* rec    = (const float*)d_in[1];
    const int*   labels = (const int*)d_in[2];
    float* out = (float*)d_out;

    unsigned short* A  = (unsigned short*)d_ws;            // 4 MB bf16 im_n (linear)
    unsigned short* Bm = A + (size_t)N * D;                // 4 MB bf16 rec_n (swizzled)
    float* diag   = (float*)(Bm + (size_t)N * D);          // 32 KB
    float* rowsum = diag + N;                              // 32 KB
    int* cnt      = (int*)(rowsum + N);                    // 4 KB
    unsigned short* members = (unsigned short*)(cnt + 1024); // 96 KB

    hipMemsetAsync(cnt, 0, 1024 * sizeof(int), stream);
    ntx_prep<<<N / 4, 256, 0, stream>>>(im, rec, labels, A, Bm, diag, rowsum, cnt, members);
    ntx_lse<<<(N / RT) * CSPLIT, 256, 0, stream>>>(A, Bm, rowsum);
    ntx_correct<<<N / 16, 256, 0, stream>>>(A, Bm, labels, cnt, members, rowsum);
    ntx_finish<<<1, 256, 0, stream>>>(diag, rowsum, out);
}